// Round 4
// baseline (560.522 us; speedup 1.0000x reference)
//
#include <hip/hip_runtime.h>

// ---------------- types / helpers ----------------
typedef short v8s __attribute__((ext_vector_type(8)));
typedef float v4f __attribute__((ext_vector_type(4)));

#define MFMA16(a, b, c) __builtin_amdgcn_mfma_f32_16x16x32_bf16(a, b, c, 0, 0, 0)

__device__ __forceinline__ unsigned short f2b(float f) {
  union { float f; unsigned int i; } v;
  v.f = f;
  unsigned int x = v.i;
  return (unsigned short)((x + 0x7fffu + ((x >> 16) & 1u)) >> 16);
}
// packed fp32x2 -> bf16x2 in one VALU op (RNE, same as f2b)
__device__ __forceinline__ unsigned int cvtpk(float lo, float hi) {
  unsigned int r;
  asm("v_cvt_pk_bf16_f32 %0, %1, %2" : "=v"(r) : "v"(lo), "v"(hi));
  return r;
}
// load 8 consecutive fp32 from global, convert to bf16 fragment (cvt_pk)
__device__ __forceinline__ v8s ldf8(const float* p) {
  float4 a = *(const float4*)p;
  float4 b = *(const float4*)(p + 4);
  union { v8s v; unsigned int d[4]; } r;
  r.d[0] = cvtpk(a.x, a.y); r.d[1] = cvtpk(a.z, a.w);
  r.d[2] = cvtpk(b.x, b.y); r.d[3] = cvtpk(b.z, b.w);
  return r.v;
}

#define SCALE 0.17677669529663687f
#define LOG2E 1.4426950408889634f
#define QSCALE (SCALE * LOG2E)   // fold base-2 exp into Q scaling

// workspace layout (bytes):
//   [0, 16 MiB)        msum[256][128][128] fp32 ((mask+sp)*log2e, [n][m])
//   +256 KiB           rpb[4][128][128]    fp32 (btab[rpi]*log2e, [n][m])
//   +96 KiB            wqh: w_qkv bf16 384x128
//   +32 KiB            wph: w_proj bf16 128x128
//   [17170432, +64MiB) oh : O intermediate bf16 [2048][128][128]   (if ws fits)
//   [84279296, +64MiB) xh : x bf16 [2048][128][128]                (if ws fits)
#define WS_RPB   16777216
#define WS_WQH   17039360
#define WS_WPH   17137664
#define WS_OH    17170432
#define WS_XH    84279296
#define WS_END_OBF 84279296ull
#define WS_END_XH  151388160ull

// ---------------- K0a: weight fp32 -> bf16 (65536 elems, grid 256) ----------
__global__ __launch_bounds__(256)
void conv_w(const float* __restrict__ wq, const float* __restrict__ wp,
            unsigned short* __restrict__ wqh, unsigned short* __restrict__ wph) {
  int i = blockIdx.x * 256 + threadIdx.x;
  if (i < 384 * 128) wqh[i] = f2b(wq[i]);
  else wph[i - 384 * 128] = f2b(wp[i - 384 * 128]);
}

// ---------------- K0b: bias precompute (grid 256 = wgrp) --------------------
__global__ __launch_bounds__(256)
void build_bias(const float* __restrict__ mask, const float* __restrict__ sp,
                const int* __restrict__ rpi, const float* __restrict__ btab,
                float* __restrict__ msum, float* __restrict__ rpb) {
  const int wgrp = blockIdx.x, tid = threadIdx.x;
  const float* mk = mask + (size_t)wgrp * 16384;
  const float* sk = sp + (size_t)wgrp * 16384;
  float* ot = msum + (size_t)wgrp * 16384;
  for (int it = 0; it < 16; ++it) {
    int i = (tid + 256 * it) * 4;
    float4 a = *(const float4*)(mk + i);
    float4 b = *(const float4*)(sk + i);
    float4 s;
    s.x = (a.x + b.x) * LOG2E; s.y = (a.y + b.y) * LOG2E;
    s.z = (a.z + b.z) * LOG2E; s.w = (a.w + b.w) * LOG2E;
    *(float4*)(ot + i) = s;
  }
  int e = wgrp * 256 + tid;            // 0..65535 over [h][n][m]
  int hh = e >> 14, r = e & 16383;
  rpb[e] = btab[rpi[r] * 4 + hh] * LOG2E;
}

// ---------------- K0c: x fp32 -> bf16 (grid 16384) --------------------------
__global__ __launch_bounds__(256)
void build_xh(const float* __restrict__ x, unsigned short* __restrict__ xh) {
  size_t i = ((size_t)blockIdx.x * 256 + threadIdx.x) * 8;
  float4 a = *(const float4*)(x + i);
  float4 b = *(const float4*)(x + i + 4);
  union { int4 v; unsigned int d[4]; } pk;
  pk.d[0] = cvtpk(a.x, a.y); pk.d[1] = cvtpk(a.z, a.w);
  pk.d[2] = cvtpk(b.x, b.y); pk.d[3] = cvtpk(b.z, b.w);
  *(int4*)(xh + i) = pk.v;
}

// ---------------- K1: fused qkv + attention per (b, h) ----------------
// XH: read precomputed bf16 x.  OBF: write O bf16 to workspace.
// K LDS stride 40 shorts / V stride 136 -> 16B-aligned single ds_read_b128.
template <bool XH, bool OBF>
__global__ __launch_bounds__(256, 4)
void attn_kernel(const float* __restrict__ xg,
                 const unsigned short* __restrict__ xhg,
                 const unsigned short* __restrict__ wqh,
                 const float* __restrict__ bq,
                 const float* __restrict__ msum,
                 const float* __restrict__ rpb,
                 float* __restrict__ o32,
                 unsigned short* __restrict__ o16) {
  // LDS: [0,10240) K (128x40 bf16)   [10240,18944) V^T (32x136 bf16)
  __shared__ alignas(16) unsigned char smem[18944];
  unsigned short* kss = (unsigned short*)smem;
  unsigned short* vs  = (unsigned short*)(smem + 10240);

  const int tid = threadIdx.x;
  const int wv = tid >> 6;
  const int lane = tid & 63;
  const int qd = lane >> 4;   // quarter 0..3
  const int t16 = lane & 15;

  const int idx = blockIdx.x;
  const int wgrp = idx >> 5;          // 0..255 : mask index
  const int rem = idx & 31;
  const int h = rem >> 3;             // head
  const int b = (rem & 7) * 256 + wgrp;  // window (b % 256 == wgrp)

  // ---- phase 1: X fragments (wave-local 32-token strip) ----
  v8s bx[2][4];
  if constexpr (XH) {
    const unsigned short* xb = xhg + (size_t)b * 16384;
    for (int nt = 0; nt < 2; ++nt)
      for (int ks = 0; ks < 4; ++ks) {
        int n = 32 * wv + nt * 16 + t16;
        bx[nt][ks] = *(const v8s*)(xb + n * 128 + ks * 32 + 8 * qd);
      }
  } else {
    const float* xb = xg + (size_t)b * 16384;
    for (int nt = 0; nt < 2; ++nt)
      for (int ks = 0; ks < 4; ++ks) {
        int n = 32 * wv + nt * 16 + t16;
        bx[nt][ks] = ldf8(xb + n * 128 + ks * 32 + 8 * qd);
      }
  }

  // q,k via out^T = W @ X^T : rows j (0..63: q then k), cols n (wave strip 32)
  v4f accqk[4][2];
  for (int jt = 0; jt < 4; ++jt)
    for (int nt = 0; nt < 2; ++nt) accqk[jt][nt] = v4f{0.f, 0.f, 0.f, 0.f};
  for (int jt = 0; jt < 4; ++jt) {
    int wbase = (jt < 2) ? (h * 32 + jt * 16) : (128 + h * 32 + (jt - 2) * 16);
    for (int ks = 0; ks < 4; ++ks) {
      v8s a = *(const v8s*)(wqh + (wbase + t16) * 128 + ks * 32 + 8 * qd);
      for (int nt = 0; nt < 2; ++nt)
        accqk[jt][nt] = MFMA16(a, bx[nt][ks], accqk[jt][nt]);
    }
  }
  // v via out = X @ Wv^T : rows n (strip 32), cols d (32)
  v4f accv[2][2];
  for (int rt = 0; rt < 2; ++rt)
    for (int ct = 0; ct < 2; ++ct) accv[rt][ct] = v4f{0.f, 0.f, 0.f, 0.f};
  for (int ct = 0; ct < 2; ++ct)
    for (int ks = 0; ks < 4; ++ks) {
      v8s bw = *(const v8s*)(wqh + (256 + h * 32 + ct * 16 + t16) * 128 + ks * 32 + 8 * qd);
      for (int rt = 0; rt < 2; ++rt)
        accv[rt][ct] = MFMA16(bx[rt][ks], bw, accv[rt][ct]);
    }

  // epilogue k (jt=2,3): packed 8B LDS stores to K[token][d] (stride 40)
  for (int jt = 2; jt < 4; ++jt)
    for (int nt = 0; nt < 2; ++nt) {
      int n = 32 * wv + nt * 16 + t16;
      int bb = 128 + h * 32 + (jt - 2) * 16 + 4 * qd;
      uint2 pk;
      pk.x = cvtpk(accqk[jt][nt][0] + bq[bb + 0], accqk[jt][nt][1] + bq[bb + 1]);
      pk.y = cvtpk(accqk[jt][nt][2] + bq[bb + 2], accqk[jt][nt][3] + bq[bb + 3]);
      *(uint2*)(kss + n * 40 + (jt - 2) * 16 + 4 * qd) = pk;
    }
  // epilogue v: store transposed V^T[d][n] (stride 136), 8B stores
  for (int ct = 0; ct < 2; ++ct) {
    int d = ct * 16 + t16;
    float bv = bq[256 + h * 32 + d];
    for (int rt = 0; rt < 2; ++rt) {
      uint2 pk;
      pk.x = cvtpk(accv[rt][ct][0] + bv, accv[rt][ct][1] + bv);
      pk.y = cvtpk(accv[rt][ct][2] + bv, accv[rt][ct][3] + bv);
      *(uint2*)(vs + d * 136 + 32 * wv + rt * 16 + 4 * qd) = pk;
    }
  }

  // ---- Q: pack bf16 dword pairs, redistribute in-register (no LDS) ----
  unsigned int qpk[2][2][2];  // [jt][nt][dw]
  for (int jt = 0; jt < 2; ++jt)
    for (int nt = 0; nt < 2; ++nt) {
      int bb = h * 32 + jt * 16 + 4 * qd;
      float v0 = (accqk[jt][nt][0] + bq[bb + 0]) * QSCALE;
      float v1 = (accqk[jt][nt][1] + bq[bb + 1]) * QSCALE;
      float v2 = (accqk[jt][nt][2] + bq[bb + 2]) * QSCALE;
      float v3 = (accqk[jt][nt][3] + bq[bb + 3]) * QSCALE;
      qpk[jt][nt][0] = cvtpk(v0, v1);
      qpk[jt][nt][1] = cvtpk(v2, v3);
    }
  const int srcA = ((qd & 1) << 5) + t16;
  const bool hiq = qd >= 2;
  v8s aq[2];
  for (int rt = 0; rt < 2; ++rt) {
    union { v8s v; unsigned int d[4]; } u;
    unsigned int a0 = __shfl((int)qpk[0][rt][0], srcA, 64);
    unsigned int b0 = __shfl((int)qpk[1][rt][0], srcA, 64);
    unsigned int a1 = __shfl((int)qpk[0][rt][1], srcA, 64);
    unsigned int b1 = __shfl((int)qpk[1][rt][1], srcA, 64);
    unsigned int a2 = __shfl((int)qpk[0][rt][0], srcA + 16, 64);
    unsigned int b2 = __shfl((int)qpk[1][rt][0], srcA + 16, 64);
    unsigned int a3 = __shfl((int)qpk[0][rt][1], srcA + 16, 64);
    unsigned int b3 = __shfl((int)qpk[1][rt][1], srcA + 16, 64);
    u.d[0] = hiq ? b0 : a0;
    u.d[1] = hiq ? b1 : a1;
    u.d[2] = hiq ? b2 : a2;
    u.d[3] = hiq ? b3 : a3;
    aq[rt] = u.v;
  }
  __syncthreads();   // the ONLY barrier: K,V visible to all waves

  // ---- phase 2: S^T = K Q^T (+ bias), softmax over m (rows), all in-lane ----
  v4f sa[2][8];   // [nt][ct]
  const v4f zero4 = {0.f, 0.f, 0.f, 0.f};
  for (int ct = 0; ct < 8; ++ct) {
    v8s bk = *(const v8s*)(kss + (ct * 16 + t16) * 40 + 8 * qd);
    for (int nt = 0; nt < 2; ++nt)
      sa[nt][ct] = MFMA16(bk, aq[nt], zero4);
  }
  // bias: msum[wgrp][n][m] + rpb[h][n][m], float4 along m (matches quad)
  {
    const float* mt = msum + (size_t)wgrp * 16384;
    const float* rb = rpb + (size_t)h * 16384;
    for (int nt = 0; nt < 2; ++nt) {
      int n = 32 * wv + nt * 16 + t16;
      const float* pm = mt + n * 128;
      const float* pr = rb + n * 128;
      for (int ct = 0; ct < 8; ++ct) {
        float4 b1 = *(const float4*)(pm + ct * 16 + 4 * qd);
        float4 b2 = *(const float4*)(pr + ct * 16 + 4 * qd);
        sa[nt][ct][0] += b1.x + b2.x;
        sa[nt][ct][1] += b1.y + b2.y;
        sa[nt][ct][2] += b1.z + b2.z;
        sa[nt][ct][3] += b1.w + b2.w;
      }
    }
  }
  // softmax denominators per column n: 32 in-lane + shfl_xor over qd bits
  float pinv[2];
  for (int nt = 0; nt < 2; ++nt) {
    float m0 = sa[nt][0][0];
    for (int ct = 0; ct < 8; ++ct)
      for (int r = 0; r < 4; ++r) m0 = fmaxf(m0, sa[nt][ct][r]);
    m0 = fmaxf(m0, __shfl_xor(m0, 16));
    m0 = fmaxf(m0, __shfl_xor(m0, 32));
    for (int ct = 0; ct < 8; ++ct)
      for (int r = 0; r < 4; ++r)
        sa[nt][ct][r] = exp2f(sa[nt][ct][r] - m0);
    float s0 = 0.f;
    for (int ct = 0; ct < 8; ++ct)
      for (int r = 0; r < 4; ++r) s0 += sa[nt][ct][r];
    s0 += __shfl_xor(s0, 16);
    s0 += __shfl_xor(s0, 32);
    pinv[nt] = 1.0f / s0;
  }

  // ---- phase 3: per n-tile: pack P, shuffle to A-frag layout, PV MFMA ----
  v8s av[2][4];
  for (int rt = 0; rt < 2; ++rt)
    for (int ks = 0; ks < 4; ++ks)
      av[rt][ks] = *(const v8s*)(vs + (rt * 16 + t16) * 136 + ks * 32 + 8 * qd);

  const int srcP0 = ((qd & 1) << 5) + t16;   // lane holding m-quads 8(qd&1)+{0..3}
  const bool hip2 = qd >= 2;                 // selects register 2ks vs 2ks+1
  for (int nt = 0; nt < 2; ++nt) {
    // pack unnormalized P (values in (0,1]) to bf16 dword pairs
    unsigned int pkd[8][2];
    for (int ct = 0; ct < 8; ++ct) {
      pkd[ct][0] = cvtpk(sa[nt][ct][0], sa[nt][ct][1]);
      pkd[ct][1] = cvtpk(sa[nt][ct][2], sa[nt][ct][3]);
    }
    // redistribute: target (qd,t16) gets P[n][m = ks*32+8qd .. +7]
    v8s bp[4];
    for (int ks = 0; ks < 4; ++ks) {
      union { v8s v; unsigned int d[4]; } u;
      unsigned int a0 = __shfl((int)pkd[2 * ks][0], srcP0, 64);
      unsigned int b0 = __shfl((int)pkd[2 * ks + 1][0], srcP0, 64);
      unsigned int a1 = __shfl((int)pkd[2 * ks][1], srcP0, 64);
      unsigned int b1 = __shfl((int)pkd[2 * ks + 1][1], srcP0, 64);
      unsigned int a2 = __shfl((int)pkd[2 * ks][0], srcP0 + 16, 64);
      unsigned int b2 = __shfl((int)pkd[2 * ks + 1][0], srcP0 + 16, 64);
      unsigned int a3 = __shfl((int)pkd[2 * ks][1], srcP0 + 16, 64);
      unsigned int b3 = __shfl((int)pkd[2 * ks + 1][1], srcP0 + 16, 64);
      u.d[0] = hip2 ? b0 : a0;
      u.d[1] = hip2 ? b1 : a1;
      u.d[2] = hip2 ? b2 : a2;
      u.d[3] = hip2 ? b3 : a3;
      bp[ks] = u.v;
    }
    // O^T[d][n] = V^T P^T for this n-tile; scale by pinv[nt] at the end
    v4f oa[2] = {zero4, zero4};
    for (int ks = 0; ks < 4; ++ks)
      for (int rt = 0; rt < 2; ++rt)
        oa[rt] = MFMA16(av[rt][ks], bp[ks], oa[rt]);
    int n = 32 * wv + nt * 16 + t16;
    float s = pinv[nt];
    if constexpr (OBF) {
      for (int rt = 0; rt < 2; ++rt) {
        uint2 pk;
        pk.x = cvtpk(oa[rt][0] * s, oa[rt][1] * s);
        pk.y = cvtpk(oa[rt][2] * s, oa[rt][3] * s);
        *(uint2*)(o16 + ((size_t)(b * 128 + n)) * 128 + h * 32 + rt * 16 + 4 * qd) = pk;
      }
    } else {
      for (int rt = 0; rt < 2; ++rt) {
        float4 pk;
        pk.x = oa[rt][0] * s;
        pk.y = oa[rt][1] * s;
        pk.z = oa[rt][2] * s;
        pk.w = oa[rt][3] * s;
        *(float4*)(o32 + ((size_t)(b * 128 + n)) * 128 + h * 32 + rt * 16 + 4 * qd) = pk;
      }
    }
  }
}

// ---------------- K2: out = O @ w_proj^T + b_proj ---------------------------
// OBF: read bf16 O from workspace (no conversion, no aliasing), write d_out.
// else: in-place on d_out (fp32 O), compiler keeps loads before stores (alias).
template <bool OBF>
__global__ __launch_bounds__(256, 4)
void proj_kernel(const unsigned short* __restrict__ wph,
                 const float* __restrict__ bpj,
                 const unsigned short* __restrict__ o16,
                 float* out) {
  const int tid = threadIdx.x;
  const int wv = tid >> 6;
  const int lane = tid & 63;
  const int qd = lane >> 4;
  const int t16 = lane & 15;
  const size_t row0 = (size_t)blockIdx.x * 128;

  // B-frags: token rows n (wave-local strip)
  v8s bo[2][4];
  if constexpr (OBF) {
    const unsigned short* src = o16 + row0 * 128;
    for (int ct = 0; ct < 2; ++ct)
      for (int ks = 0; ks < 4; ++ks) {
        int n = 32 * wv + ct * 16 + t16;
        bo[ct][ks] = *(const v8s*)(src + n * 128 + ks * 32 + 8 * qd);
      }
  } else {
    const float* src = out + row0 * 128;
    for (int ct = 0; ct < 2; ++ct)
      for (int ks = 0; ks < 4; ++ks) {
        int n = 32 * wv + ct * 16 + t16;
        bo[ct][ks] = ldf8(src + n * 128 + ks * 32 + 8 * qd);
      }
  }
  v4f acc[8][2];
  for (int rt = 0; rt < 8; ++rt)
    for (int ct = 0; ct < 2; ++ct) acc[rt][ct] = v4f{0.f, 0.f, 0.f, 0.f};
  for (int rt = 0; rt < 8; ++rt)
    for (int ks = 0; ks < 4; ++ks) {
      v8s a = *(const v8s*)(wph + (rt * 16 + t16) * 128 + ks * 32 + 8 * qd);
      for (int ct = 0; ct < 2; ++ct)
        acc[rt][ct] = MFMA16(a, bo[ct][ks], acc[rt][ct]);
    }
  for (int rt = 0; rt < 8; ++rt) {
    float4 bj = *(const float4*)(bpj + rt * 16 + 4 * qd);
    for (int ct = 0; ct < 2; ++ct) {
      int n = 32 * wv + ct * 16 + t16;
      float4 pk;
      pk.x = acc[rt][ct][0] + bj.x;
      pk.y = acc[rt][ct][1] + bj.y;
      pk.z = acc[rt][ct][2] + bj.z;
      pk.w = acc[rt][ct][3] + bj.w;
      *(float4*)(out + (row0 + n) * 128 + rt * 16 + 4 * qd) = pk;
    }
  }
}

// ---------------- launch ----------------
extern "C" void kernel_launch(void* const* d_in, const int* in_sizes, int n_in,
                              void* d_out, int out_size, void* d_ws, size_t ws_size,
                              hipStream_t stream) {
  (void)in_sizes; (void)n_in; (void)out_size;
  const float* xg   = (const float*)d_in[0];
  const int*   rpi  = (const int*)d_in[1];
  const float* mask = (const float*)d_in[2];
  const float* sp   = (const float*)d_in[3];
  const float* wq   = (const float*)d_in[4];
  const float* bq   = (const float*)d_in[5];
  const float* btab = (const float*)d_in[6];
  const float* wp   = (const float*)d_in[7];
  const float* bpj  = (const float*)d_in[8];
  float* out = (float*)d_out;

  float* msum = (float*)d_ws;                                    // 16 MiB
  float* rpb  = (float*)((char*)d_ws + WS_RPB);                  // 256 KiB
  unsigned short* wqh = (unsigned short*)((char*)d_ws + WS_WQH); // 96 KiB
  unsigned short* wph = (unsigned short*)((char*)d_ws + WS_WPH); // 32 KiB
  unsigned short* oh  = (unsigned short*)((char*)d_ws + WS_OH);  // 64 MiB
  unsigned short* xh  = (unsigned short*)((char*)d_ws + WS_XH);  // 64 MiB

  const bool obf = ws_size >= WS_END_OBF;
  const bool xhp = ws_size >= WS_END_XH;

  conv_w<<<256, 256, 0, stream>>>(wq, wp, wqh, wph);
  build_bias<<<256, 256, 0, stream>>>(mask, sp, rpi, btab, msum, rpb);
  if (xhp) {
    build_xh<<<16384, 256, 0, stream>>>(xg, xh);
    attn_kernel<true, true><<<8192, 256, 0, stream>>>(xg, xh, wqh, bq, msum, rpb, out, oh);
  } else if (obf) {
    attn_kernel<false, true><<<8192, 256, 0, stream>>>(xg, xh, wqh, bq, msum, rpb, out, oh);
  } else {
    attn_kernel<false, false><<<8192, 256, 0, stream>>>(xg, xh, wqh, bq, msum, rpb, out, oh);
  }
  if (obf) proj_kernel<true><<<2048, 256, 0, stream>>>(wph, bpj, oh, out);
  else     proj_kernel<false><<<2048, 256, 0, stream>>>(wph, bpj, oh, out);
}

// Round 5
// 542.798 us; speedup vs baseline: 1.0327x; 1.0327x over previous
//
#include <hip/hip_runtime.h>

// ---------------- types / helpers ----------------
typedef short v8s __attribute__((ext_vector_type(8)));
typedef float v4f __attribute__((ext_vector_type(4)));

#define MFMA16(a, b, c) __builtin_amdgcn_mfma_f32_16x16x32_bf16(a, b, c, 0, 0, 0)

__device__ __forceinline__ unsigned short f2b(float f) {
  union { float f; unsigned int i; } v;
  v.f = f;
  unsigned int x = v.i;
  return (unsigned short)((x + 0x7fffu + ((x >> 16) & 1u)) >> 16);
}
// packed fp32x2 -> bf16x2 in one VALU op (RNE, same as f2b)
__device__ __forceinline__ unsigned int cvtpk(float lo, float hi) {
  unsigned int r;
  asm("v_cvt_pk_bf16_f32 %0, %1, %2" : "=v"(r) : "v"(lo), "v"(hi));
  return r;
}

#define SCALE 0.17677669529663687f
#define LOG2E 1.4426950408889634f
#define QSCALE (SCALE * LOG2E)   // fold base-2 exp into Q scaling

// workspace layout (bytes):
//   [0, 16 MiB)   msum[256][128][128] fp32 ((mask+sp)*log2e, [n][m])
//   +256 KiB      rpb[4][128][128]    fp32 (btab[rpi]*log2e, [n][m])
//   +96 KiB       wqh: w_qkv bf16 384x128
//   +32 KiB       wph: w_proj bf16 128x128
#define WS_RPB 16777216
#define WS_WQH 17039360
#define WS_WPH 17137664

// ---------------- K0a: weight fp32 -> bf16 (65536 elems, grid 256) ----------
__global__ __launch_bounds__(256)
void conv_w(const float* __restrict__ wq, const float* __restrict__ wp,
            unsigned short* __restrict__ wqh, unsigned short* __restrict__ wph) {
  int i = blockIdx.x * 256 + threadIdx.x;
  if (i < 384 * 128) wqh[i] = f2b(wq[i]);
  else wph[i - 384 * 128] = f2b(wp[i - 384 * 128]);
}

// ---------------- K0b: bias precompute (grid 256 = wgrp) --------------------
__global__ __launch_bounds__(256)
void build_bias(const float* __restrict__ mask, const float* __restrict__ sp,
                const int* __restrict__ rpi, const float* __restrict__ btab,
                float* __restrict__ msum, float* __restrict__ rpb) {
  const int wgrp = blockIdx.x, tid = threadIdx.x;
  const float* mk = mask + (size_t)wgrp * 16384;
  const float* sk = sp + (size_t)wgrp * 16384;
  float* ot = msum + (size_t)wgrp * 16384;
  for (int it = 0; it < 16; ++it) {
    int i = (tid + 256 * it) * 4;
    float4 a = *(const float4*)(mk + i);
    float4 b = *(const float4*)(sk + i);
    float4 s;
    s.x = (a.x + b.x) * LOG2E; s.y = (a.y + b.y) * LOG2E;
    s.z = (a.z + b.z) * LOG2E; s.w = (a.w + b.w) * LOG2E;
    *(float4*)(ot + i) = s;
  }
  int e = wgrp * 256 + tid;            // 0..65535 over [h][n][m]
  int hh = e >> 14, r = e & 16383;
  rpb[e] = btab[rpi[r] * 4 + hh] * LOG2E;
}

// ---------------- K1: FULLY FUSED qkv + attention + proj per window ---------
// 2048 blocks x 1024 threads (16 waves = 4 heads x 4 token-strips).
// LDS: [0,32768)  X bf16 128x128 XOR-swizzled  (aliased by O after barrier 1)
//      [0,34816)  O bf16 [128 n][136 c]
//      [34816 + h*10240)  K_h bf16 [128][40]
//      [75776 + h*8704)   V^T_h bf16 [32][136]
// Barriers: 0 (X staged), 1 (K/V ready, X dead), 2 (O ready).
__global__ __launch_bounds__(1024, 4)
void attn_fused(const float* __restrict__ xg,
                const unsigned short* __restrict__ wqh,
                const float* __restrict__ bq,
                const float* __restrict__ msum,
                const float* __restrict__ rpb,
                const unsigned short* __restrict__ wph,
                const float* __restrict__ bpj,
                float* __restrict__ out) {
  __shared__ alignas(16) unsigned char smem[110592];
  unsigned short* xs = (unsigned short*)smem;
  unsigned short* os = (unsigned short*)smem;

  const int tid = threadIdx.x;
  const int wid = tid >> 6;
  const int s = wid & 3;      // token strip 0..3 (32 tokens each)
  const int h = wid >> 2;     // head 0..3
  const int lane = tid & 63;
  const int qd = lane >> 4;   // quarter 0..3
  const int t16 = lane & 15;

  const int idx = blockIdx.x;
  const int wgrp = idx >> 3;             // 0..255 : mask index
  const int b = (idx & 7) * 256 + wgrp;  // window (b % 256 == wgrp)

  unsigned short* kss = (unsigned short*)(smem + 34816 + h * 10240);
  unsigned short* vs  = (unsigned short*)(smem + 75776 + h * 8704);

  // ---- stage X once per window (fp32 -> bf16, 16B-granule XOR swizzle) ----
  {
    const float* src = xg + (size_t)b * 16384;
    for (int it = 0; it < 2; ++it) {
      int gl = tid + 1024 * it;          // 0..2047
      int row = gl >> 4, g = gl & 15;
      const float4* s4 = (const float4*)(src + row * 128 + g * 8);
      float4 a = s4[0], c = s4[1];
      union { int4 v; unsigned int d[4]; } pk;
      pk.d[0] = cvtpk(a.x, a.y); pk.d[1] = cvtpk(a.z, a.w);
      pk.d[2] = cvtpk(c.x, c.y); pk.d[3] = cvtpk(c.z, c.w);
      *(int4*)(xs + row * 128 + ((g ^ (row & 15)) << 3)) = pk.v;
    }
  }
  __syncthreads();   // barrier 0: X visible

  // ---- phase 1: qkv for (head h, strip s) ----
  v8s bx[2][4];
  for (int nt = 0; nt < 2; ++nt)
    for (int ks = 0; ks < 4; ++ks) {
      int n = 32 * s + nt * 16 + t16;
      int g = ks * 4 + qd;
      bx[nt][ks] = *(const v8s*)(xs + n * 128 + ((g ^ (n & 15)) << 3));
    }

  // q,k via out^T = W @ X^T : rows j (0..63: q then k), cols n (strip 32)
  v4f accqk[4][2];
  for (int jt = 0; jt < 4; ++jt)
    for (int nt = 0; nt < 2; ++nt) accqk[jt][nt] = v4f{0.f, 0.f, 0.f, 0.f};
  for (int jt = 0; jt < 4; ++jt) {
    int wbase = (jt < 2) ? (h * 32 + jt * 16) : (128 + h * 32 + (jt - 2) * 16);
    for (int ks = 0; ks < 4; ++ks) {
      v8s a = *(const v8s*)(wqh + (wbase + t16) * 128 + ks * 32 + 8 * qd);
      for (int nt = 0; nt < 2; ++nt)
        accqk[jt][nt] = MFMA16(a, bx[nt][ks], accqk[jt][nt]);
    }
  }
  // v via out = X @ Wv^T : rows n (strip 32), cols d (32)
  v4f accv[2][2];
  for (int rt = 0; rt < 2; ++rt)
    for (int ct = 0; ct < 2; ++ct) accv[rt][ct] = v4f{0.f, 0.f, 0.f, 0.f};
  for (int ct = 0; ct < 2; ++ct)
    for (int ks = 0; ks < 4; ++ks) {
      v8s bw = *(const v8s*)(wqh + (256 + h * 32 + ct * 16 + t16) * 128 + ks * 32 + 8 * qd);
      for (int rt = 0; rt < 2; ++rt)
        accv[rt][ct] = MFMA16(bx[rt][ks], bw, accv[rt][ct]);
    }

  // epilogue k (jt=2,3): packed 8B LDS stores to K_h[token][d] (stride 40)
  for (int jt = 2; jt < 4; ++jt)
    for (int nt = 0; nt < 2; ++nt) {
      int n = 32 * s + nt * 16 + t16;
      int bb = 128 + h * 32 + (jt - 2) * 16 + 4 * qd;
      uint2 pk;
      pk.x = cvtpk(accqk[jt][nt][0] + bq[bb + 0], accqk[jt][nt][1] + bq[bb + 1]);
      pk.y = cvtpk(accqk[jt][nt][2] + bq[bb + 2], accqk[jt][nt][3] + bq[bb + 3]);
      *(uint2*)(kss + n * 40 + (jt - 2) * 16 + 4 * qd) = pk;
    }
  // epilogue v: store transposed V^T_h[d][n] (stride 136), 8B stores
  for (int ct = 0; ct < 2; ++ct) {
    int d = ct * 16 + t16;
    float bv = bq[256 + h * 32 + d];
    for (int rt = 0; rt < 2; ++rt) {
      uint2 pk;
      pk.x = cvtpk(accv[rt][ct][0] + bv, accv[rt][ct][1] + bv);
      pk.y = cvtpk(accv[rt][ct][2] + bv, accv[rt][ct][3] + bv);
      *(uint2*)(vs + d * 136 + 32 * s + rt * 16 + 4 * qd) = pk;
    }
  }

  // ---- Q: pack bf16 dword pairs, redistribute in-register (no LDS) ----
  unsigned int qpk[2][2][2];  // [jt][nt][dw]
  for (int jt = 0; jt < 2; ++jt)
    for (int nt = 0; nt < 2; ++nt) {
      int bb = h * 32 + jt * 16 + 4 * qd;
      float v0 = (accqk[jt][nt][0] + bq[bb + 0]) * QSCALE;
      float v1 = (accqk[jt][nt][1] + bq[bb + 1]) * QSCALE;
      float v2 = (accqk[jt][nt][2] + bq[bb + 2]) * QSCALE;
      float v3 = (accqk[jt][nt][3] + bq[bb + 3]) * QSCALE;
      qpk[jt][nt][0] = cvtpk(v0, v1);
      qpk[jt][nt][1] = cvtpk(v2, v3);
    }
  const int srcA = ((qd & 1) << 5) + t16;
  const bool hiq = qd >= 2;
  v8s aq[2];
  for (int rt = 0; rt < 2; ++rt) {
    union { v8s v; unsigned int d[4]; } u;
    unsigned int a0 = __shfl((int)qpk[0][rt][0], srcA, 64);
    unsigned int b0 = __shfl((int)qpk[1][rt][0], srcA, 64);
    unsigned int a1 = __shfl((int)qpk[0][rt][1], srcA, 64);
    unsigned int b1 = __shfl((int)qpk[1][rt][1], srcA, 64);
    unsigned int a2 = __shfl((int)qpk[0][rt][0], srcA + 16, 64);
    unsigned int b2 = __shfl((int)qpk[1][rt][0], srcA + 16, 64);
    unsigned int a3 = __shfl((int)qpk[0][rt][1], srcA + 16, 64);
    unsigned int b3 = __shfl((int)qpk[1][rt][1], srcA + 16, 64);
    u.d[0] = hiq ? b0 : a0;
    u.d[1] = hiq ? b1 : a1;
    u.d[2] = hiq ? b2 : a2;
    u.d[3] = hiq ? b3 : a3;
    aq[rt] = u.v;
  }
  __syncthreads();   // barrier 1: K,V visible; X dead (O may alias now)

  // ---- phase 2: S^T = K Q^T (+ bias), softmax over m (rows), in-lane ----
  v4f sa[2][8];   // [nt][ct]
  const v4f zero4 = {0.f, 0.f, 0.f, 0.f};
  for (int ct = 0; ct < 8; ++ct) {
    v8s bk = *(const v8s*)(kss + (ct * 16 + t16) * 40 + 8 * qd);
    for (int nt = 0; nt < 2; ++nt)
      sa[nt][ct] = MFMA16(bk, aq[nt], zero4);
  }
  // bias: msum[wgrp][n][m] + rpb[h][n][m], float4 along m (matches quad)
  {
    const float* mt = msum + (size_t)wgrp * 16384;
    const float* rb = rpb + (size_t)h * 16384;
    for (int nt = 0; nt < 2; ++nt) {
      int n = 32 * s + nt * 16 + t16;
      const float* pm = mt + n * 128;
      const float* pr = rb + n * 128;
      for (int ct = 0; ct < 8; ++ct) {
        float4 b1 = *(const float4*)(pm + ct * 16 + 4 * qd);
        float4 b2 = *(const float4*)(pr + ct * 16 + 4 * qd);
        sa[nt][ct][0] += b1.x + b2.x;
        sa[nt][ct][1] += b1.y + b2.y;
        sa[nt][ct][2] += b1.z + b2.z;
        sa[nt][ct][3] += b1.w + b2.w;
      }
    }
  }
  // softmax denominators per column n: 32 in-lane + shfl_xor over qd bits
  float pinv[2];
  for (int nt = 0; nt < 2; ++nt) {
    float m0 = sa[nt][0][0];
    for (int ct = 0; ct < 8; ++ct)
      for (int r = 0; r < 4; ++r) m0 = fmaxf(m0, sa[nt][ct][r]);
    m0 = fmaxf(m0, __shfl_xor(m0, 16));
    m0 = fmaxf(m0, __shfl_xor(m0, 32));
    for (int ct = 0; ct < 8; ++ct)
      for (int r = 0; r < 4; ++r)
        sa[nt][ct][r] = exp2f(sa[nt][ct][r] - m0);
    float s0 = 0.f;
    for (int ct = 0; ct < 8; ++ct)
      for (int r = 0; r < 4; ++r) s0 += sa[nt][ct][r];
    s0 += __shfl_xor(s0, 16);
    s0 += __shfl_xor(s0, 32);
    pinv[nt] = 1.0f / s0;
  }

  // ---- phase 3: per n-tile: pack P, shuffle to B-frag layout, PV -> O LDS --
  v8s av[2][4];
  for (int rt = 0; rt < 2; ++rt)
    for (int ks = 0; ks < 4; ++ks)
      av[rt][ks] = *(const v8s*)(vs + (rt * 16 + t16) * 136 + ks * 32 + 8 * qd);

  const int srcP0 = ((qd & 1) << 5) + t16;
  const bool hip2 = qd >= 2;
  for (int nt = 0; nt < 2; ++nt) {
    unsigned int pkd[8][2];
    for (int ct = 0; ct < 8; ++ct) {
      pkd[ct][0] = cvtpk(sa[nt][ct][0], sa[nt][ct][1]);
      pkd[ct][1] = cvtpk(sa[nt][ct][2], sa[nt][ct][3]);
    }
    v8s bp[4];
    for (int ks = 0; ks < 4; ++ks) {
      union { v8s v; unsigned int d[4]; } u;
      unsigned int a0 = __shfl((int)pkd[2 * ks][0], srcP0, 64);
      unsigned int b0 = __shfl((int)pkd[2 * ks + 1][0], srcP0, 64);
      unsigned int a1 = __shfl((int)pkd[2 * ks][1], srcP0, 64);
      unsigned int b1 = __shfl((int)pkd[2 * ks + 1][1], srcP0, 64);
      unsigned int a2 = __shfl((int)pkd[2 * ks][0], srcP0 + 16, 64);
      unsigned int b2 = __shfl((int)pkd[2 * ks + 1][0], srcP0 + 16, 64);
      unsigned int a3 = __shfl((int)pkd[2 * ks][1], srcP0 + 16, 64);
      unsigned int b3 = __shfl((int)pkd[2 * ks + 1][1], srcP0 + 16, 64);
      u.d[0] = hip2 ? b0 : a0;
      u.d[1] = hip2 ? b1 : a1;
      u.d[2] = hip2 ? b2 : a2;
      u.d[3] = hip2 ? b3 : a3;
      bp[ks] = u.v;
    }
    v4f oa[2] = {zero4, zero4};
    for (int ks = 0; ks < 4; ++ks)
      for (int rt = 0; rt < 2; ++rt)
        oa[rt] = MFMA16(av[rt][ks], bp[ks], oa[rt]);
    int n = 32 * s + nt * 16 + t16;
    float sv = pinv[nt];
    for (int rt = 0; rt < 2; ++rt) {
      uint2 pk;
      pk.x = cvtpk(oa[rt][0] * sv, oa[rt][1] * sv);
      pk.y = cvtpk(oa[rt][2] * sv, oa[rt][3] * sv);
      *(uint2*)(os + n * 136 + h * 32 + rt * 16 + 4 * qd) = pk;
    }
  }
  __syncthreads();   // barrier 2: O tile complete

  // ---- fused proj: out[n][c_out] = O[n][:] @ Wp^T + bpj ----
  // wave wid -> token tile tn = wid>>1 (16 tokens), channel tiles tc0..tc0+3.
  {
    const int tn = wid >> 1;
    const int tc0 = (wid & 1) * 4;
    v8s ao[4];
    for (int ks = 0; ks < 4; ++ks)
      ao[ks] = *(const v8s*)(os + (tn * 16 + t16) * 136 + ks * 32 + 8 * qd);
    for (int tc = 0; tc < 4; ++tc) {
      int co = (tc0 + tc) * 16;
      v4f acc = zero4;
      for (int ks = 0; ks < 4; ++ks) {
        v8s bwp = *(const v8s*)(wph + (co + t16) * 128 + ks * 32 + 8 * qd);
        acc = MFMA16(ao[ks], bwp, acc);
      }
      float bj = bpj[co + t16];
      size_t rowb = (size_t)b * 128 + tn * 16 + 4 * qd;
      out[(rowb + 0) * 128 + co + t16] = acc[0] + bj;
      out[(rowb + 1) * 128 + co + t16] = acc[1] + bj;
      out[(rowb + 2) * 128 + co + t16] = acc[2] + bj;
      out[(rowb + 3) * 128 + co + t16] = acc[3] + bj;
    }
  }
}

// ---------------- launch ----------------
extern "C" void kernel_launch(void* const* d_in, const int* in_sizes, int n_in,
                              void* d_out, int out_size, void* d_ws, size_t ws_size,
                              hipStream_t stream) {
  (void)in_sizes; (void)n_in; (void)out_size; (void)ws_size;
  const float* xg   = (const float*)d_in[0];
  const int*   rpi  = (const int*)d_in[1];
  const float* mask = (const float*)d_in[2];
  const float* sp   = (const float*)d_in[3];
  const float* wq   = (const float*)d_in[4];
  const float* bq   = (const float*)d_in[5];
  const float* btab = (const float*)d_in[6];
  const float* wp   = (const float*)d_in[7];
  const float* bpj  = (const float*)d_in[8];
  float* out = (float*)d_out;

  float* msum = (float*)d_ws;                                    // 16 MiB
  float* rpb  = (float*)((char*)d_ws + WS_RPB);                  // 256 KiB
  unsigned short* wqh = (unsigned short*)((char*)d_ws + WS_WQH); // 96 KiB
  unsigned short* wph = (unsigned short*)((char*)d_ws + WS_WPH); // 32 KiB

  conv_w<<<256, 256, 0, stream>>>(wq, wp, wqh, wph);
  build_bias<<<256, 256, 0, stream>>>(mask, sp, rpi, btab, msum, rpb);
  attn_fused<<<2048, 1024, 0, stream>>>(xg, wqh, bq, msum, rpb, wph, bpj, out);
}